// Round 18
// baseline (58.356 us; speedup 1.0000x reference)
//
#include <hip/hip_runtime.h>
#include <math.h>

// ContrastiveLoss: B=16384, D=64, fp32 in, scalar fp32 out.
// loss_i = logsumexp_j(sim[i,j]) - sim[i,i];  out = mean_i(loss_i)
// sim = normalize_rows(A) @ normalize_rows(B)^T / 0.07
//
// Round 18: R17 base (simexp 40.3us: NWAVE=8, TT=4, JC=32, 64KB LDS staged
// once, Schraudolph bit-exp, XOR swizzle; pipes VALU 40% + MFMA 31% + LDS 25%
// ~= saturated issue bandwidth). Two attributable changes:
// (1) aux diet 2: rowloss does in-block reduction (64 blocks, 1 row/thread,
//     coalesced) -> 64 block sums; mean = one wave over 64 floats. Removes
//     the ~4us serial single-block mean walk.
// (2) #pragma unroll 4 on the jt loop: amortize loop/addressing VALU overhead
//     (measured VALU ~16us vs ~7us element floor) without R3's full-unroll
//     register blowup. Guard: VGPR must stay <=64.

#define NROWS 16384
#define DIM 64
#define INV_T 14.285714285714286f           // 1/0.07
#define LOG2E 1.44269504088896340736f
#define LN2   0.69314718055994530942f
// A pre-scale: INV_T * LOG2E * 2^23  (MFMA acc = 2^23 * log2-logit)
#define SCALE (INV_T * LOG2E * 8388608.0f)
// Schraudolph bias: (127 - 0.0432) * 2^23, balanced max rel error +-3.0%
#define BIASF 1064990828.0f

#define JC     32                           // j-chunks
#define JPC    (NROWS / JC)                 // 512 j per chunk
#define NTILES (JPC / 16)                   // 32 B-tiles per chunk
#define TT     4                            // A row-tiles per wave (64 rows)
#define WR     (TT * 16)                    // 64 rows per wave
#define NWAVE  8                            // waves per block (512 threads)
#define BROWS  (NWAVE * WR)                 // 512 rows per block
#define ROWB   (DIM * 2)                    // 128 bytes per bf16 row
#define LDSB   (JPC * ROWB)                 // 64 KiB
#define TILB   (16 * ROWB)                  // 2048 B per 16-row tile

typedef __attribute__((ext_vector_type(8))) short bf16x8;  // 8 bf16 = 4 VGPRs
typedef __attribute__((ext_vector_type(4))) float f32x4;

static __device__ __forceinline__ unsigned short f2bf(float f) {
    unsigned int u = __float_as_uint(f);
    unsigned int r = (u + 0x7fffu + ((u >> 16) & 1u)) >> 16;   // RNE
    return (unsigned short)r;
}

// ------- kernel 1: normalize A,B rows -> bf16; also diag*INV_T -------------
__global__ __launch_bounds__(256) void nrm_bf16_kernel(
        const float* __restrict__ A, const float* __restrict__ B,
        unsigned short* __restrict__ Ab, unsigned short* __restrict__ Bb,
        float* __restrict__ diag) {
    int row  = (blockIdx.x * 256 + threadIdx.x) >> 6;
    int lane = threadIdx.x & 63;
    float xa = A[row * DIM + lane];
    float xb = B[row * DIM + lane];
    float saa = xa * xa, sbb = xb * xb, sab = xa * xb;
    #pragma unroll
    for (int m = 32; m >= 1; m >>= 1) {
        saa += __shfl_xor(saa, m, 64);
        sbb += __shfl_xor(sbb, m, 64);
        sab += __shfl_xor(sab, m, 64);
    }
    Ab[row * DIM + lane] = f2bf(xa * rsqrtf(saa) * SCALE);
    Bb[row * DIM + lane] = f2bf(xb * rsqrtf(sbb));
    if (lane == 0) diag[row] = sab * rsqrtf(saa * sbb) * INV_T;
}

// -------- kernel 2: LDS-staged MFMA sim tiles + bit-exp row-sum partials ---
// One block = one 64KB j-chunk staged once; 8 waves x 64 A-rows each.
__global__ __launch_bounds__(NWAVE * 64) void simexp_kernel(
        const unsigned short* __restrict__ Ab,
        const unsigned short* __restrict__ Bb,
        float* __restrict__ partials) {
    __shared__ __align__(1024) unsigned char lds[LDSB];
    const int lane = threadIdx.x & 63;
    const int wid  = threadIdx.x >> 6;                  // wave in block
    const int jc   = blockIdx.x & (JC - 1);
    const int rb   = blockIdx.x / JC;                   // 0..31
    const int i0   = rb * BROWS + wid * WR;             // wave's first A row
    const int lr   = lane & 15;                         // fragment row/col
    const int lk   = lane >> 4;                         // k-group (x8 bf16)

    // ---- stage B chunk ONCE: linear LDS dest, XOR-permuted global src ----
    // LDS(row, col16) holds global(row, col16 ^ (row&7)); each instr covers
    // 8 rows (1 KiB), so row&7 == lane>>3 inside the instr.  (validated r5)
    const unsigned char* gB = (const unsigned char*)Bb + (size_t)jc * JPC * ROWB;
    const int perm = ((lane >> 3) << 7) | ((((lane & 7) ^ (lane >> 3))) << 4);
    #pragma unroll
    for (int i = 0; i < LDSB / 1024 / NWAVE; ++i) {     // 8 slabs per wave
        const int off = (wid * (LDSB / 1024 / NWAVE) + i) * 1024;
        __builtin_amdgcn_global_load_lds(
            (const __attribute__((address_space(1))) void*)(gB + off + perm),
            (__attribute__((address_space(3))) void*)(&lds[off]),
            16, 0, 0);
    }

    // ---- A fragments (global/L2 loads overlap the staging latency) -------
    bf16x8 a[TT][2];
    #pragma unroll
    for (int t = 0; t < TT; ++t) {
        const unsigned short* ap = Ab + (size_t)(i0 + t * 16 + lr) * DIM + lk * 8;
        a[t][0] = *(const bf16x8*)(ap);
        a[t][1] = *(const bf16x8*)(ap + 32);
    }

    float es[TT][4];
    #pragma unroll
    for (int t = 0; t < TT; ++t)
        #pragma unroll
        for (int r = 0; r < 4; ++r) es[t][r] = 0.0f;

    // Drain the staging DMA (vmcnt(0); lgkm/exp free) before the barrier.
    __builtin_amdgcn_s_waitcnt(0x0f70);
    __syncthreads();

    // ds_read bases: row lr, col16 = lk (frag0) / lk^4 (frag1), un-swizzled
    // via the same XOR; loop-invariant since row&7 == lr&7 for every tile.
    const unsigned char* lp0 = &lds[lr * ROWB + (((lk    ) ^ (lr & 7)) << 4)];
    const unsigned char* lp1 = &lds[lr * ROWB + (((lk ^ 4) ^ (lr & 7)) << 4)];

    // MFMA C input = Schraudolph bias: acc = 2^23*x + (127-sigma)*2^23.
    const f32x4 bias = {BIASF, BIASF, BIASF, BIASF};

    // ---- prologue: tile 0 -> accp ----
    bf16x8 c0 = *(const bf16x8*)(lp0);
    bf16x8 c1 = *(const bf16x8*)(lp1);
    f32x4 accp[TT];
    #pragma unroll
    for (int t = 0; t < TT; ++t) {
        accp[t] = __builtin_amdgcn_mfma_f32_16x16x32_bf16(a[t][0], c0, bias, 0, 0, 0);
        accp[t] = __builtin_amdgcn_mfma_f32_16x16x32_bf16(a[t][1], c1, accp[t], 0, 0, 0);
    }

    // ---- steady state: ds_read(jt) | bit-exp(jt-1) | MFMA(jt) ----
    #pragma unroll 4
    for (int jt = 1; jt < NTILES; ++jt) {
        bf16x8 n0 = *(const bf16x8*)(lp0 + jt * TILB);
        bf16x8 n1 = *(const bf16x8*)(lp1 + jt * TILB);
        #pragma unroll
        for (int t = 0; t < TT; ++t)
            #pragma unroll
            for (int r = 0; r < 4; ++r)
                es[t][r] += __int_as_float((int)accp[t][r]);
        #pragma unroll
        for (int t = 0; t < TT; ++t) {
            accp[t] = __builtin_amdgcn_mfma_f32_16x16x32_bf16(a[t][0], n0, bias, 0, 0, 0);
            accp[t] = __builtin_amdgcn_mfma_f32_16x16x32_bf16(a[t][1], n1, accp[t], 0, 0, 0);
        }
    }
    // ---- epilogue: bit-exp of last tile ----
    #pragma unroll
    for (int t = 0; t < TT; ++t)
        #pragma unroll
        for (int r = 0; r < 4; ++r)
            es[t][r] += __int_as_float((int)accp[t][r]);

    // es[t][r]: partial over this lane's 16-col slice of row i0+t*16+lk*4+r.
    #pragma unroll
    for (int t = 0; t < TT; ++t)
        #pragma unroll
        for (int r = 0; r < 4; ++r) {
            float v = es[t][r];
            v += __shfl_xor(v, 1, 64);
            v += __shfl_xor(v, 2, 64);
            v += __shfl_xor(v, 4, 64);
            v += __shfl_xor(v, 8, 64);
            es[t][r] = v;
        }

    if (lr == 0) {                                      // lanes 0,16,32,48
        float* pout = partials + (size_t)jc * NROWS + i0;
        #pragma unroll
        for (int t = 0; t < TT; ++t) {
            f32x4 v = {es[t][0], es[t][1], es[t][2], es[t][3]};
            *(f32x4*)(pout + t * 16 + lk * 4) = v;      // rows lk*4..lk*4+3
        }
    }
}

// -------- kernel 3: per-row loss + in-block sum -> 64 block sums -----------
__global__ __launch_bounds__(256) void rowloss_kernel(
        const float* __restrict__ partials, const float* __restrict__ diag,
        float* __restrict__ blocksum) {
    int row = blockIdx.x * 256 + threadIdx.x;           // 1 row per thread
    float S = 0.0f;
    #pragma unroll
    for (int c = 0; c < JC; ++c) S += partials[(size_t)c * NROWS + row];
    float loss = LN2 * __builtin_amdgcn_logf(S) - diag[row];
    // block-reduce 256 losses -> 1 (deterministic tree)
    __shared__ float red[4];
    #pragma unroll
    for (int m = 32; m >= 1; m >>= 1) loss += __shfl_xor(loss, m, 64);
    if ((threadIdx.x & 63) == 0) red[threadIdx.x >> 6] = loss;
    __syncthreads();
    if (threadIdx.x == 0)
        blocksum[blockIdx.x] = (red[0] + red[1]) + (red[2] + red[3]);
}

// -------- kernel 4: mean = sum of 64 block sums / NROWS --------------------
__global__ __launch_bounds__(64) void mean_kernel(
        const float* __restrict__ blocksum, float* __restrict__ out) {
    float s = blocksum[threadIdx.x];                    // 64 values, 1 wave
    #pragma unroll
    for (int m = 32; m >= 1; m >>= 1) s += __shfl_xor(s, m, 64);
    if (threadIdx.x == 0) out[0] = s * (1.0f / NROWS);
}

extern "C" void kernel_launch(void* const* d_in, const int* in_sizes, int n_in,
                              void* d_out, int out_size, void* d_ws, size_t ws_size,
                              hipStream_t stream) {
    const float* A  = (const float*)d_in[0];
    const float* Bm = (const float*)d_in[1];
    float* out = (float*)d_out;

    unsigned short* Ab = (unsigned short*)d_ws;                 // 2 MiB
    unsigned short* Bb = Ab + (size_t)NROWS * DIM;              // 2 MiB
    float* partials    = (float*)(Bb + (size_t)NROWS * DIM);    // 2 MiB
    float* diag        = partials + (size_t)JC * NROWS;         // 64 KiB
    float* blocksum    = diag + NROWS;                          // 256 B

    nrm_bf16_kernel<<<NROWS / 4, 256, 0, stream>>>(A, Bm, Ab, Bb, diag);
    simexp_kernel<<<JC * (NROWS / BROWS), NWAVE * 64, 0, stream>>>(Ab, Bb, partials);
    rowloss_kernel<<<NROWS / 256, 256, 0, stream>>>(partials, diag, blocksum);
    mean_kernel<<<1, 64, 0, stream>>>(blocksum, out);
}

// Round 19
// 53.434 us; speedup vs baseline: 1.0921x; 1.0921x over previous
//
#include <hip/hip_runtime.h>
#include <math.h>

// ContrastiveLoss: B=16384, D=64, fp32 in, scalar fp32 out.
// loss_i = logsumexp_j(sim[i,j]) - sim[i,i];  out = mean_i(loss_i)
// sim = normalize_rows(A) @ normalize_rows(B)^T / 0.07
//
// Round 19: revert R18's unroll-4 (VGPR 56->124, occ 29->19%, simexp 40->56us
// -- the pre-committed guard fired), keep R18's aux diet (block-reducing
// rowloss + 64-float mean). simexp is R15/R17's engine verbatim: NWAVE=8,
// TT=4, JC=32, 64KB LDS chunk staged once via global_load_lds(16B) with the
// validated XOR swizzle, Schraudolph bit-exp in the MFMA C operand, 56 VGPR,
// measured 40.0/40.3us twice. Pipes at this point: VALU 40% + MFMA 31% +
// LDS ~25% ~= saturated issue bandwidth in overlap.

#define NROWS 16384
#define DIM 64
#define INV_T 14.285714285714286f           // 1/0.07
#define LOG2E 1.44269504088896340736f
#define LN2   0.69314718055994530942f
// A pre-scale: INV_T * LOG2E * 2^23  (MFMA acc = 2^23 * log2-logit)
#define SCALE (INV_T * LOG2E * 8388608.0f)
// Schraudolph bias: (127 - 0.0432) * 2^23, balanced max rel error +-3.0%
#define BIASF 1064990828.0f

#define JC     32                           // j-chunks
#define JPC    (NROWS / JC)                 // 512 j per chunk
#define NTILES (JPC / 16)                   // 32 B-tiles per chunk
#define TT     4                            // A row-tiles per wave (64 rows)
#define WR     (TT * 16)                    // 64 rows per wave
#define NWAVE  8                            // waves per block (512 threads)
#define BROWS  (NWAVE * WR)                 // 512 rows per block
#define ROWB   (DIM * 2)                    // 128 bytes per bf16 row
#define LDSB   (JPC * ROWB)                 // 64 KiB
#define TILB   (16 * ROWB)                  // 2048 B per 16-row tile

typedef __attribute__((ext_vector_type(8))) short bf16x8;  // 8 bf16 = 4 VGPRs
typedef __attribute__((ext_vector_type(4))) float f32x4;

static __device__ __forceinline__ unsigned short f2bf(float f) {
    unsigned int u = __float_as_uint(f);
    unsigned int r = (u + 0x7fffu + ((u >> 16) & 1u)) >> 16;   // RNE
    return (unsigned short)r;
}

// ------- kernel 1: normalize A,B rows -> bf16; also diag*INV_T -------------
__global__ __launch_bounds__(256) void nrm_bf16_kernel(
        const float* __restrict__ A, const float* __restrict__ B,
        unsigned short* __restrict__ Ab, unsigned short* __restrict__ Bb,
        float* __restrict__ diag) {
    int row  = (blockIdx.x * 256 + threadIdx.x) >> 6;
    int lane = threadIdx.x & 63;
    float xa = A[row * DIM + lane];
    float xb = B[row * DIM + lane];
    float saa = xa * xa, sbb = xb * xb, sab = xa * xb;
    #pragma unroll
    for (int m = 32; m >= 1; m >>= 1) {
        saa += __shfl_xor(saa, m, 64);
        sbb += __shfl_xor(sbb, m, 64);
        sab += __shfl_xor(sab, m, 64);
    }
    Ab[row * DIM + lane] = f2bf(xa * rsqrtf(saa) * SCALE);
    Bb[row * DIM + lane] = f2bf(xb * rsqrtf(sbb));
    if (lane == 0) diag[row] = sab * rsqrtf(saa * sbb) * INV_T;
}

// -------- kernel 2: LDS-staged MFMA sim tiles + bit-exp row-sum partials ---
// One block = one 64KB j-chunk staged once; 8 waves x 64 A-rows each.
__global__ __launch_bounds__(NWAVE * 64) void simexp_kernel(
        const unsigned short* __restrict__ Ab,
        const unsigned short* __restrict__ Bb,
        float* __restrict__ partials) {
    __shared__ __align__(1024) unsigned char lds[LDSB];
    const int lane = threadIdx.x & 63;
    const int wid  = threadIdx.x >> 6;                  // wave in block
    const int jc   = blockIdx.x & (JC - 1);
    const int rb   = blockIdx.x / JC;                   // 0..31
    const int i0   = rb * BROWS + wid * WR;             // wave's first A row
    const int lr   = lane & 15;                         // fragment row/col
    const int lk   = lane >> 4;                         // k-group (x8 bf16)

    // ---- stage B chunk ONCE: linear LDS dest, XOR-permuted global src ----
    // LDS(row, col16) holds global(row, col16 ^ (row&7)); each instr covers
    // 8 rows (1 KiB), so row&7 == lane>>3 inside the instr.  (validated r5)
    const unsigned char* gB = (const unsigned char*)Bb + (size_t)jc * JPC * ROWB;
    const int perm = ((lane >> 3) << 7) | ((((lane & 7) ^ (lane >> 3))) << 4);
    #pragma unroll
    for (int i = 0; i < LDSB / 1024 / NWAVE; ++i) {     // 8 slabs per wave
        const int off = (wid * (LDSB / 1024 / NWAVE) + i) * 1024;
        __builtin_amdgcn_global_load_lds(
            (const __attribute__((address_space(1))) void*)(gB + off + perm),
            (__attribute__((address_space(3))) void*)(&lds[off]),
            16, 0, 0);
    }

    // ---- A fragments (global/L2 loads overlap the staging latency) -------
    bf16x8 a[TT][2];
    #pragma unroll
    for (int t = 0; t < TT; ++t) {
        const unsigned short* ap = Ab + (size_t)(i0 + t * 16 + lr) * DIM + lk * 8;
        a[t][0] = *(const bf16x8*)(ap);
        a[t][1] = *(const bf16x8*)(ap + 32);
    }

    float es[TT][4];
    #pragma unroll
    for (int t = 0; t < TT; ++t)
        #pragma unroll
        for (int r = 0; r < 4; ++r) es[t][r] = 0.0f;

    // Drain the staging DMA (vmcnt(0); lgkm/exp free) before the barrier.
    __builtin_amdgcn_s_waitcnt(0x0f70);
    __syncthreads();

    // ds_read bases: row lr, col16 = lk (frag0) / lk^4 (frag1), un-swizzled
    // via the same XOR; loop-invariant since row&7 == lr&7 for every tile.
    const unsigned char* lp0 = &lds[lr * ROWB + (((lk    ) ^ (lr & 7)) << 4)];
    const unsigned char* lp1 = &lds[lr * ROWB + (((lk ^ 4) ^ (lr & 7)) << 4)];

    // MFMA C input = Schraudolph bias: acc = 2^23*x + (127-sigma)*2^23.
    const f32x4 bias = {BIASF, BIASF, BIASF, BIASF};

    // ---- prologue: tile 0 -> accp ----
    bf16x8 c0 = *(const bf16x8*)(lp0);
    bf16x8 c1 = *(const bf16x8*)(lp1);
    f32x4 accp[TT];
    #pragma unroll
    for (int t = 0; t < TT; ++t) {
        accp[t] = __builtin_amdgcn_mfma_f32_16x16x32_bf16(a[t][0], c0, bias, 0, 0, 0);
        accp[t] = __builtin_amdgcn_mfma_f32_16x16x32_bf16(a[t][1], c1, accp[t], 0, 0, 0);
    }

    // ---- steady state: ds_read(jt) | bit-exp(jt-1) | MFMA(jt) ----
    for (int jt = 1; jt < NTILES; ++jt) {
        bf16x8 n0 = *(const bf16x8*)(lp0 + jt * TILB);
        bf16x8 n1 = *(const bf16x8*)(lp1 + jt * TILB);
        #pragma unroll
        for (int t = 0; t < TT; ++t)
            #pragma unroll
            for (int r = 0; r < 4; ++r)
                es[t][r] += __int_as_float((int)accp[t][r]);
        #pragma unroll
        for (int t = 0; t < TT; ++t) {
            accp[t] = __builtin_amdgcn_mfma_f32_16x16x32_bf16(a[t][0], n0, bias, 0, 0, 0);
            accp[t] = __builtin_amdgcn_mfma_f32_16x16x32_bf16(a[t][1], n1, accp[t], 0, 0, 0);
        }
    }
    // ---- epilogue: bit-exp of last tile ----
    #pragma unroll
    for (int t = 0; t < TT; ++t)
        #pragma unroll
        for (int r = 0; r < 4; ++r)
            es[t][r] += __int_as_float((int)accp[t][r]);

    // es[t][r]: partial over this lane's 16-col slice of row i0+t*16+lk*4+r.
    #pragma unroll
    for (int t = 0; t < TT; ++t)
        #pragma unroll
        for (int r = 0; r < 4; ++r) {
            float v = es[t][r];
            v += __shfl_xor(v, 1, 64);
            v += __shfl_xor(v, 2, 64);
            v += __shfl_xor(v, 4, 64);
            v += __shfl_xor(v, 8, 64);
            es[t][r] = v;
        }

    if (lr == 0) {                                      // lanes 0,16,32,48
        float* pout = partials + (size_t)jc * NROWS + i0;
        #pragma unroll
        for (int t = 0; t < TT; ++t) {
            f32x4 v = {es[t][0], es[t][1], es[t][2], es[t][3]};
            *(f32x4*)(pout + t * 16 + lk * 4) = v;      // rows lk*4..lk*4+3
        }
    }
}

// -------- kernel 3: per-row loss + in-block sum -> 64 block sums -----------
__global__ __launch_bounds__(256) void rowloss_kernel(
        const float* __restrict__ partials, const float* __restrict__ diag,
        float* __restrict__ blocksum) {
    int row = blockIdx.x * 256 + threadIdx.x;           // 1 row per thread
    float S = 0.0f;
    #pragma unroll
    for (int c = 0; c < JC; ++c) S += partials[(size_t)c * NROWS + row];
    float loss = LN2 * __builtin_amdgcn_logf(S) - diag[row];
    // block-reduce 256 losses -> 1 (deterministic tree)
    __shared__ float red[4];
    #pragma unroll
    for (int m = 32; m >= 1; m >>= 1) loss += __shfl_xor(loss, m, 64);
    if ((threadIdx.x & 63) == 0) red[threadIdx.x >> 6] = loss;
    __syncthreads();
    if (threadIdx.x == 0)
        blocksum[blockIdx.x] = (red[0] + red[1]) + (red[2] + red[3]);
}

// -------- kernel 4: mean = sum of 64 block sums / NROWS --------------------
__global__ __launch_bounds__(64) void mean_kernel(
        const float* __restrict__ blocksum, float* __restrict__ out) {
    float s = blocksum[threadIdx.x];                    // 64 values, 1 wave
    #pragma unroll
    for (int m = 32; m >= 1; m >>= 1) s += __shfl_xor(s, m, 64);
    if (threadIdx.x == 0) out[0] = s * (1.0f / NROWS);
}

extern "C" void kernel_launch(void* const* d_in, const int* in_sizes, int n_in,
                              void* d_out, int out_size, void* d_ws, size_t ws_size,
                              hipStream_t stream) {
    const float* A  = (const float*)d_in[0];
    const float* Bm = (const float*)d_in[1];
    float* out = (float*)d_out;

    unsigned short* Ab = (unsigned short*)d_ws;                 // 2 MiB
    unsigned short* Bb = Ab + (size_t)NROWS * DIM;              // 2 MiB
    float* partials    = (float*)(Bb + (size_t)NROWS * DIM);    // 2 MiB
    float* diag        = partials + (size_t)JC * NROWS;         // 64 KiB
    float* blocksum    = diag + NROWS;                          // 256 B

    nrm_bf16_kernel<<<NROWS / 4, 256, 0, stream>>>(A, Bm, Ab, Bb, diag);
    simexp_kernel<<<JC * (NROWS / BROWS), NWAVE * 64, 0, stream>>>(Ab, Bb, partials);
    rowloss_kernel<<<NROWS / 256, 256, 0, stream>>>(partials, diag, blocksum);
    mean_kernel<<<1, 64, 0, stream>>>(blocksum, out);
}

// Round 20
// 47.724 us; speedup vs baseline: 1.2228x; 1.1196x over previous
//
#include <hip/hip_runtime.h>
#include <math.h>

// ContrastiveLoss: B=16384, D=64, fp32 in, scalar fp32 out.
// loss_i = logsumexp_j(sim[i,j]) - sim[i,i];  out = mean_i(loss_i)
// sim = normalize_rows(A) @ normalize_rows(B)^T / 0.07
//
// Round 20: operand swap. R19 reproduced simexp 40.1us (3rd time) with the
// epilogue shfl-reduce costing ~64 ds_permute-class ops/wave (~5us chip) and
// 16 es registers. Computing mfma(B_tile, A_tile) transposes the accumulator:
// col = A-row (lane&15), row = j -- so each lane accumulates ONE A-row's
// partial sum over its j-slice. es: [TT][4] -> [TT] (-12 VGPR); reduce: 64
// shfls -> 8 (xor 16,32 across lane-groups); write: coalesced 16-lane f32.
// Fragment layouts make the swap free (B-operand loads == our A-row loads).
// Same MFMA count, same cvt+add count, bit-equivalent numerics.

#define NROWS 16384
#define DIM 64
#define INV_T 14.285714285714286f           // 1/0.07
#define LOG2E 1.44269504088896340736f
#define LN2   0.69314718055994530942f
// A pre-scale: INV_T * LOG2E * 2^23  (MFMA acc = 2^23 * log2-logit)
#define SCALE (INV_T * LOG2E * 8388608.0f)
// Schraudolph bias: (127 - 0.0432) * 2^23, balanced max rel error +-3.0%
#define BIASF 1064990828.0f

#define JC     32                           // j-chunks
#define JPC    (NROWS / JC)                 // 512 j per chunk
#define NTILES (JPC / 16)                   // 32 B-tiles per chunk
#define TT     4                            // A row-tiles per wave (64 rows)
#define WR     (TT * 16)                    // 64 rows per wave
#define NWAVE  8                            // waves per block (512 threads)
#define BROWS  (NWAVE * WR)                 // 512 rows per block
#define ROWB   (DIM * 2)                    // 128 bytes per bf16 row
#define LDSB   (JPC * ROWB)                 // 64 KiB
#define TILB   (16 * ROWB)                  // 2048 B per 16-row tile

typedef __attribute__((ext_vector_type(8))) short bf16x8;  // 8 bf16 = 4 VGPRs
typedef __attribute__((ext_vector_type(4))) float f32x4;

static __device__ __forceinline__ unsigned short f2bf(float f) {
    unsigned int u = __float_as_uint(f);
    unsigned int r = (u + 0x7fffu + ((u >> 16) & 1u)) >> 16;   // RNE
    return (unsigned short)r;
}

// ------- kernel 1: normalize A,B rows -> bf16; also diag*INV_T -------------
__global__ __launch_bounds__(256) void nrm_bf16_kernel(
        const float* __restrict__ A, const float* __restrict__ B,
        unsigned short* __restrict__ Ab, unsigned short* __restrict__ Bb,
        float* __restrict__ diag) {
    int row  = (blockIdx.x * 256 + threadIdx.x) >> 6;
    int lane = threadIdx.x & 63;
    float xa = A[row * DIM + lane];
    float xb = B[row * DIM + lane];
    float saa = xa * xa, sbb = xb * xb, sab = xa * xb;
    #pragma unroll
    for (int m = 32; m >= 1; m >>= 1) {
        saa += __shfl_xor(saa, m, 64);
        sbb += __shfl_xor(sbb, m, 64);
        sab += __shfl_xor(sab, m, 64);
    }
    Ab[row * DIM + lane] = f2bf(xa * rsqrtf(saa) * SCALE);
    Bb[row * DIM + lane] = f2bf(xb * rsqrtf(sbb));
    if (lane == 0) diag[row] = sab * rsqrtf(saa * sbb) * INV_T;
}

// -------- kernel 2: LDS-staged MFMA sim tiles + bit-exp row-sum partials ---
// One block = one 64KB j-chunk staged once; 8 waves x 64 A-rows each.
// SWAPPED MFMA: acc[row=j, col=i] -> lane-local j-sums per A-row.
__global__ __launch_bounds__(NWAVE * 64) void simexp_kernel(
        const unsigned short* __restrict__ Ab,
        const unsigned short* __restrict__ Bb,
        float* __restrict__ partials) {
    __shared__ __align__(1024) unsigned char lds[LDSB];
    const int lane = threadIdx.x & 63;
    const int wid  = threadIdx.x >> 6;                  // wave in block
    const int jc   = blockIdx.x & (JC - 1);
    const int rb   = blockIdx.x / JC;                   // 0..31
    const int i0   = rb * BROWS + wid * WR;             // wave's first A row
    const int lr   = lane & 15;                         // fragment row/col
    const int lk   = lane >> 4;                         // k-group (x8 bf16)

    // ---- stage B chunk ONCE: linear LDS dest, XOR-permuted global src ----
    // LDS(row, col16) holds global(row, col16 ^ (row&7)); each instr covers
    // 8 rows (1 KiB), so row&7 == lane>>3 inside the instr.  (validated r5)
    const unsigned char* gB = (const unsigned char*)Bb + (size_t)jc * JPC * ROWB;
    const int perm = ((lane >> 3) << 7) | ((((lane & 7) ^ (lane >> 3))) << 4);
    #pragma unroll
    for (int i = 0; i < LDSB / 1024 / NWAVE; ++i) {     // 8 slabs per wave
        const int off = (wid * (LDSB / 1024 / NWAVE) + i) * 1024;
        __builtin_amdgcn_global_load_lds(
            (const __attribute__((address_space(1))) void*)(gB + off + perm),
            (__attribute__((address_space(3))) void*)(&lds[off]),
            16, 0, 0);
    }

    // ---- A fragments; as MFMA B-operand: col=lane&15 -> A-row i0+t*16+lr --
    bf16x8 a[TT][2];
    #pragma unroll
    for (int t = 0; t < TT; ++t) {
        const unsigned short* ap = Ab + (size_t)(i0 + t * 16 + lr) * DIM + lk * 8;
        a[t][0] = *(const bf16x8*)(ap);
        a[t][1] = *(const bf16x8*)(ap + 32);
    }

    float es[TT];                                       // 1 reg per tile now
    #pragma unroll
    for (int t = 0; t < TT; ++t) es[t] = 0.0f;

    // Drain the staging DMA (vmcnt(0); lgkm/exp free) before the barrier.
    __builtin_amdgcn_s_waitcnt(0x0f70);
    __syncthreads();

    // ds_read bases: row lr, col16 = lk (frag0) / lk^4 (frag1), un-swizzled
    // via the same XOR; loop-invariant since row&7 == lr&7 for every tile.
    const unsigned char* lp0 = &lds[lr * ROWB + (((lk    ) ^ (lr & 7)) << 4)];
    const unsigned char* lp1 = &lds[lr * ROWB + (((lk ^ 4) ^ (lr & 7)) << 4)];

    // MFMA C input = Schraudolph bias: acc = 2^23*x + (127-sigma)*2^23.
    const f32x4 bias = {BIASF, BIASF, BIASF, BIASF};

    // ---- prologue: tile 0 -> accp (swapped operands) ----
    bf16x8 c0 = *(const bf16x8*)(lp0);
    bf16x8 c1 = *(const bf16x8*)(lp1);
    f32x4 accp[TT];
    #pragma unroll
    for (int t = 0; t < TT; ++t) {
        accp[t] = __builtin_amdgcn_mfma_f32_16x16x32_bf16(c0, a[t][0], bias, 0, 0, 0);
        accp[t] = __builtin_amdgcn_mfma_f32_16x16x32_bf16(c1, a[t][1], accp[t], 0, 0, 0);
    }

    // ---- steady state: ds_read(jt) | bit-exp(jt-1) | MFMA(jt) ----
    for (int jt = 1; jt < NTILES; ++jt) {
        bf16x8 n0 = *(const bf16x8*)(lp0 + jt * TILB);
        bf16x8 n1 = *(const bf16x8*)(lp1 + jt * TILB);
        #pragma unroll
        for (int t = 0; t < TT; ++t) {
            es[t] += (__int_as_float((int)accp[t][0]) +
                      __int_as_float((int)accp[t][1])) +
                     (__int_as_float((int)accp[t][2]) +
                      __int_as_float((int)accp[t][3]));
        }
        #pragma unroll
        for (int t = 0; t < TT; ++t) {
            accp[t] = __builtin_amdgcn_mfma_f32_16x16x32_bf16(n0, a[t][0], bias, 0, 0, 0);
            accp[t] = __builtin_amdgcn_mfma_f32_16x16x32_bf16(n1, a[t][1], accp[t], 0, 0, 0);
        }
    }
    // ---- epilogue: bit-exp of last tile ----
    #pragma unroll
    for (int t = 0; t < TT; ++t) {
        es[t] += (__int_as_float((int)accp[t][0]) +
                  __int_as_float((int)accp[t][1])) +
                 (__int_as_float((int)accp[t][2]) +
                  __int_as_float((int)accp[t][3]));
    }

    // es[t]: partial over this lane's j-slice for A-row i0+t*16+lr.
    // Reduce across the 4 lane-groups (xor 16, 32); lanes 0-15 write.
    #pragma unroll
    for (int t = 0; t < TT; ++t) {
        float v = es[t];
        v += __shfl_xor(v, 16, 64);
        v += __shfl_xor(v, 32, 64);
        es[t] = v;
    }
    if (lane < 16) {
        float* pout = partials + (size_t)jc * NROWS + i0;
        #pragma unroll
        for (int t = 0; t < TT; ++t)
            pout[t * 16 + lane] = es[t];                // coalesced 64B
    }
}

// -------- kernel 3: per-row loss + in-block sum -> 64 block sums -----------
__global__ __launch_bounds__(256) void rowloss_kernel(
        const float* __restrict__ partials, const float* __restrict__ diag,
        float* __restrict__ blocksum) {
    int row = blockIdx.x * 256 + threadIdx.x;           // 1 row per thread
    float S = 0.0f;
    #pragma unroll
    for (int c = 0; c < JC; ++c) S += partials[(size_t)c * NROWS + row];
    float loss = LN2 * __builtin_amdgcn_logf(S) - diag[row];
    // block-reduce 256 losses -> 1 (deterministic tree)
    __shared__ float red[4];
    #pragma unroll
    for (int m = 32; m >= 1; m >>= 1) loss += __shfl_xor(loss, m, 64);
    if ((threadIdx.x & 63) == 0) red[threadIdx.x >> 6] = loss;
    __syncthreads();
    if (threadIdx.x == 0)
        blocksum[blockIdx.x] = (red[0] + red[1]) + (red[2] + red[3]);
}

// -------- kernel 4: mean = sum of 64 block sums / NROWS --------------------
__global__ __launch_bounds__(64) void mean_kernel(
        const float* __restrict__ blocksum, float* __restrict__ out) {
    float s = blocksum[threadIdx.x];                    // 64 values, 1 wave
    #pragma unroll
    for (int m = 32; m >= 1; m >>= 1) s += __shfl_xor(s, m, 64);
    if (threadIdx.x == 0) out[0] = s * (1.0f / NROWS);
}

extern "C" void kernel_launch(void* const* d_in, const int* in_sizes, int n_in,
                              void* d_out, int out_size, void* d_ws, size_t ws_size,
                              hipStream_t stream) {
    const float* A  = (const float*)d_in[0];
    const float* Bm = (const float*)d_in[1];
    float* out = (float*)d_out;

    unsigned short* Ab = (unsigned short*)d_ws;                 // 2 MiB
    unsigned short* Bb = Ab + (size_t)NROWS * DIM;              // 2 MiB
    float* partials    = (float*)(Bb + (size_t)NROWS * DIM);    // 2 MiB
    float* diag        = partials + (size_t)JC * NROWS;         // 64 KiB
    float* blocksum    = diag + NROWS;                          // 256 B

    nrm_bf16_kernel<<<NROWS / 4, 256, 0, stream>>>(A, Bm, Ab, Bb, diag);
    simexp_kernel<<<JC * (NROWS / BROWS), NWAVE * 64, 0, stream>>>(Ab, Bb, partials);
    rowloss_kernel<<<NROWS / 256, 256, 0, stream>>>(partials, diag, blocksum);
    mean_kernel<<<1, 64, 0, stream>>>(blocksum, out);
}